// Round 4
// baseline (77.615 us; speedup 1.0000x reference)
//
#include <hip/hip_runtime.h>

#define BB 8
#define HH 512
#define WW 512
#define HW (HH * WW)

#define TW 32          // tile width
#define TH 32          // tile height
#define LR 38          // staged rows (TH+6)
#define LC 38          // staged cols (TW+6)
#define LS 40          // LDS row stride (dwords); rows stay 16B-aligned
#define PLANE (LR * LS)

__device__ __forceinline__ int reflect512(int v) {
    v = v < 0 ? -v : v;
    return v >= 512 ? 1022 - v : v;
}

__global__ __launch_bounds__(256, 4) void bilateral4(const float* __restrict__ in,
                                                     float* __restrict__ out) {
    __shared__ float lds[3 * PLANE];   // 18,240 B

    const int bx = blockIdx.x & 15;          // 512/32 = 16 tiles per dim
    const int by = (blockIdx.x >> 4) & 15;
    const int b  = blockIdx.x >> 8;
    const int x0 = bx * TW, y0 = by * TH;
    const int tx = threadIdx.x;              // 0..7   (owns 4 adjacent cols)
    const int ty = threadIdx.y;              // 0..31  (owns 1 row)
    const int tid = ty * 8 + tx;

    const float* __restrict__ src = in + (size_t)b * 3 * HW;

    // ---- stage 38x38 tile+halo per channel (reflect once, here) ----
    for (int e = tid; e < 3 * LR * LC; e += 256) {
        int ch  = e / (LR * LC);
        int rem = e - ch * (LR * LC);
        int r   = rem / LC;
        int c   = rem - r * LC;
        lds[ch * PLANE + r * LS + c] =
            src[ch * HW + reflect512(y0 + r - 3) * WW + reflect512(x0 + c - 3)];
    }
    __syncthreads();

    const int c0 = 4 * tx;                   // window base col (16B aligned)
    const float* L0 = lds;
    const float* L1 = lds + PLANE;
    const float* L2 = lds + 2 * PLANE;

    float cc0[4], cc1[4], cc2[4];
    #pragma unroll
    for (int p = 0; p < 4; ++p) {
        int ci = (ty + 3) * LS + c0 + 3 + p;
        cc0[p] = L0[ci]; cc1[p] = L1[ci]; cc2[p] = L2[ci];
    }

    float n0[4] = {0, 0, 0, 0}, n1[4] = {0, 0, 0, 0};
    float n2[4] = {0, 0, 0, 0}, dn[4] = {0, 0, 0, 0};

    const float sw[7] = {0.98984784f, 0.99547514f, 0.99886688f, 1.0f,
                         0.99886688f, 0.99547514f, 0.98984784f};
    const float K2 = -0.00721347520445f;     // (-0.5/10^2) * log2(e)

    #pragma unroll
    for (int dy = 0; dy < 7; ++dy) {
        const int ro = (ty + dy) * LS + c0;
        float q0[10], q1[10], q2[10];
        {   // 10 window cols per channel: b128 + b128 + b64, all bank-balanced
            float4 a = *(const float4*)(L0 + ro);
            float4 bq = *(const float4*)(L0 + ro + 4);
            float2 cq = *(const float2*)(L0 + ro + 8);
            q0[0]=a.x; q0[1]=a.y; q0[2]=a.z; q0[3]=a.w;
            q0[4]=bq.x; q0[5]=bq.y; q0[6]=bq.z; q0[7]=bq.w;
            q0[8]=cq.x; q0[9]=cq.y;
        }
        {
            float4 a = *(const float4*)(L1 + ro);
            float4 bq = *(const float4*)(L1 + ro + 4);
            float2 cq = *(const float2*)(L1 + ro + 8);
            q1[0]=a.x; q1[1]=a.y; q1[2]=a.z; q1[3]=a.w;
            q1[4]=bq.x; q1[5]=bq.y; q1[6]=bq.z; q1[7]=bq.w;
            q1[8]=cq.x; q1[9]=cq.y;
        }
        {
            float4 a = *(const float4*)(L2 + ro);
            float4 bq = *(const float4*)(L2 + ro + 4);
            float2 cq = *(const float2*)(L2 + ro + 8);
            q2[0]=a.x; q2[1]=a.y; q2[2]=a.z; q2[3]=a.w;
            q2[4]=bq.x; q2[5]=bq.y; q2[6]=bq.z; q2[7]=bq.w;
            q2[8]=cq.x; q2[9]=cq.y;
        }

        const float wy = sw[dy];
        #pragma unroll
        for (int dx = 0; dx < 7; ++dx) {
            const float sc = wy * sw[dx];    // literal after unroll
            #pragma unroll
            for (int p = 0; p < 4; ++p) {
                float a0 = q0[dx + p], a1 = q1[dx + p], a2 = q2[dx + p];
                float d = fabsf(a0 - cc0[p]) + fabsf(a1 - cc1[p]) + fabsf(a2 - cc2[p]);
                float w = sc * __builtin_amdgcn_exp2f(K2 * (d * d));
                n0[p] += w * a0; n1[p] += w * a1; n2[p] += w * a2; dn[p] += w;
            }
        }
    }

    float4 o0, o1, o2;
    {
        float i0 = 1.0f / dn[0], i1 = 1.0f / dn[1], i2 = 1.0f / dn[2], i3 = 1.0f / dn[3];
        o0 = make_float4(n0[0]*i0, n0[1]*i1, n0[2]*i2, n0[3]*i3);
        o1 = make_float4(n1[0]*i0, n1[1]*i1, n1[2]*i2, n1[3]*i3);
        o2 = make_float4(n2[0]*i0, n2[1]*i1, n2[2]*i2, n2[3]*i3);
    }
    size_t ob = (size_t)b * 3 * HW + (size_t)(y0 + ty) * WW + x0 + c0;
    *(float4*)(out + ob)          = o0;
    *(float4*)(out + ob + HW)     = o1;
    *(float4*)(out + ob + 2*HW)   = o2;
}

extern "C" void kernel_launch(void* const* d_in, const int* in_sizes, int n_in,
                              void* d_out, int out_size, void* d_ws, size_t ws_size,
                              hipStream_t stream) {
    const float* in = (const float*)d_in[0];
    float* out = (float*)d_out;
    dim3 block(8, 32, 1);
    int blocks = (WW / TW) * (HH / TH) * BB;   // 16*16*8 = 2048
    bilateral4<<<blocks, block, 0, stream>>>(in, out);
}

// Round 5
// 56.364 us; speedup vs baseline: 1.3770x; 1.3770x over previous
//
#include <hip/hip_runtime.h>

#define BB 8
#define HH 512
#define WW 512
#define HW (HH * WW)

#define TW 32   // tile width (pixels)
#define TH 16   // tile height
#define LR 22   // tile rows in LDS  (TH + 6)
#define LC 38   // tile cols in LDS  (TW + 6)
#define LS 40   // LDS row stride
#define PLANE (LR * LS)

__device__ __forceinline__ int reflect512(int v) {
    v = v < 0 ? -v : v;
    return v >= 512 ? 1022 - v : v;
}

__global__ __launch_bounds__(256) void bilateral_poly(const float* __restrict__ in,
                                                      float* __restrict__ out) {
    __shared__ float lds[3 * PLANE];   // 10,560 B

    const int bx = blockIdx.x & 15;           // 512/TW = 16
    const int by = (blockIdx.x >> 4) & 31;    // 512/TH = 32
    const int b  = blockIdx.x >> 9;
    const int x0 = bx * TW, y0 = by * TH;
    const int tid = threadIdx.y * 16 + threadIdx.x;

    const float* __restrict__ src = in + (size_t)b * 3 * HW;

    // ---- stage tile + 3-halo into LDS (reflect handled once, here) ----
    for (int e = tid; e < 3 * LR * LC; e += 256) {
        int ch  = e / (LR * LC);
        int rem = e - ch * (LR * LC);
        int r   = rem / LC;
        int c   = rem - r * LC;
        lds[ch * PLANE + r * LS + c] =
            src[ch * HW + reflect512(y0 + r - 3) * WW + reflect512(x0 + c - 3)];
    }
    __syncthreads();

    // ---- compute: each thread owns 2 adjacent output pixels ----
    const int tx = threadIdx.x, ty = threadIdx.y;
    const int wbase = ty * LS + 2 * tx;
    const float* L0 = lds;
    const float* L1 = lds + PLANE;
    const float* L2 = lds + 2 * PLANE;

    const float cA0 = L0[wbase + 3 * LS + 3], cB0 = L0[wbase + 3 * LS + 4];
    const float cA1 = L1[wbase + 3 * LS + 3], cB1 = L1[wbase + 3 * LS + 4];
    const float cA2 = L2[wbase + 3 * LS + 3], cB2 = L2[wbase + 3 * LS + 4];

    float nA0 = 0.f, nA1 = 0.f, nA2 = 0.f, dnA = 0.f;
    float nB0 = 0.f, nB1 = 0.f, nB2 = 0.f, dnB = 0.f;

    // unnormalized spatial gaussian (normalization cancels in num/den)
    const float swv[7] = {0.98984784f, 0.99547514f, 0.99886688f, 1.0f,
                          0.99886688f, 0.99547514f, 0.98984784f};
    // exp(-0.005*d2) ~= 1 - 0.005*d2 + 1.25e-5*d2^2  (|err| <= u^3/6 = 1.5e-5
    // for d <= 3) -> 2 FMAs, no transcendental
    const float C1 = -5.0e-3f;
    const float C2 = 1.25e-5f;

    #pragma unroll
    for (int dy = 0; dy < 7; ++dy) {
        const int ro = wbase + dy * LS;
        float2 u0 = *(const float2*)(L0 + ro);
        float2 u1 = *(const float2*)(L0 + ro + 2);
        float2 u2 = *(const float2*)(L0 + ro + 4);
        float2 u3 = *(const float2*)(L0 + ro + 6);
        float2 v0 = *(const float2*)(L1 + ro);
        float2 v1 = *(const float2*)(L1 + ro + 2);
        float2 v2 = *(const float2*)(L1 + ro + 4);
        float2 v3 = *(const float2*)(L1 + ro + 6);
        float2 w0 = *(const float2*)(L2 + ro);
        float2 w1 = *(const float2*)(L2 + ro + 2);
        float2 w2 = *(const float2*)(L2 + ro + 4);
        float2 w3 = *(const float2*)(L2 + ro + 6);

        float q0[8] = {u0.x, u0.y, u1.x, u1.y, u2.x, u2.y, u3.x, u3.y};
        float q1[8] = {v0.x, v0.y, v1.x, v1.y, v2.x, v2.y, v3.x, v3.y};
        float q2[8] = {w0.x, w0.y, w1.x, w1.y, w2.x, w2.y, w3.x, w3.y};

        const float wy = swv[dy];
        #pragma unroll
        for (int dx = 0; dx < 7; ++dx) {
            const float sc = wy * swv[dx];    // literal after unroll
            {   // pixel A: window col dx
                float d  = fabsf(q0[dx] - cA0) + fabsf(q1[dx] - cA1) + fabsf(q2[dx] - cA2);
                float d2 = d * d;
                float w  = sc * fmaf(fmaf(C2, d2, C1), d2, 1.0f);
                nA0 += w * q0[dx]; nA1 += w * q1[dx]; nA2 += w * q2[dx]; dnA += w;
            }
            {   // pixel B: window col dx+1
                float d  = fabsf(q0[dx+1] - cB0) + fabsf(q1[dx+1] - cB1) + fabsf(q2[dx+1] - cB2);
                float d2 = d * d;
                float w  = sc * fmaf(fmaf(C2, d2, C1), d2, 1.0f);
                nB0 += w * q0[dx+1]; nB1 += w * q1[dx+1]; nB2 += w * q2[dx+1]; dnB += w;
            }
        }
    }

    const float iA = 1.0f / dnA, iB = 1.0f / dnB;
    size_t ob = (size_t)b * 3 * HW + (size_t)(y0 + ty) * WW + x0 + 2 * tx;
    *(float2*)(out + ob)          = make_float2(nA0 * iA, nB0 * iB);
    *(float2*)(out + ob + HW)     = make_float2(nA1 * iA, nB1 * iB);
    *(float2*)(out + ob + 2 * HW) = make_float2(nA2 * iA, nB2 * iB);
}

extern "C" void kernel_launch(void* const* d_in, const int* in_sizes, int n_in,
                              void* d_out, int out_size, void* d_ws, size_t ws_size,
                              hipStream_t stream) {
    const float* in = (const float*)d_in[0];
    float* out = (float*)d_out;
    dim3 block(16, 16, 1);
    int blocks = (WW / TW) * (HH / TH) * BB;   // 16*32*8 = 4096
    bilateral_poly<<<blocks, block, 0, stream>>>(in, out);
}